// Round 1
// baseline (2858.913 us; speedup 1.0000x reference)
//
#include <hip/hip_runtime.h>
#include <hip/hip_fp16.h>

#define B_ 2048
#define T_ 25
#define CL_ 97

typedef float f32x4 __attribute__((ext_vector_type(4)));
typedef _Float16 f16x8 __attribute__((ext_vector_type(8)));
typedef _Float16 f16x2 __attribute__((ext_vector_type(2)));

#define DI static __device__ __forceinline__

DI float fast_tanh(float x) { return 1.0f - 2.0f / (__expf(2.0f * x) + 1.0f); }
DI float fast_sigm(float x) { return 1.0f / (1.0f + __expf(-x)); }

// ---------------- pack / convert kernels (run once per call) ----------------

__global__ void k_convx(const float* __restrict__ x, _Float16* __restrict__ xh, int n8) {
    int i = blockIdx.x * 256 + threadIdx.x;
    if (i >= n8) return;
    const f32x4 v0 = *(const f32x4*)(x + (long long)i * 8);
    const f32x4 v1 = *(const f32x4*)(x + (long long)i * 8 + 4);
    f16x8 o;
    o[0] = (_Float16)v0[0]; o[1] = (_Float16)v0[1]; o[2] = (_Float16)v0[2]; o[3] = (_Float16)v0[3];
    o[4] = (_Float16)v1[0]; o[5] = (_Float16)v1[1]; o[6] = (_Float16)v1[2]; o[7] = (_Float16)v1[3];
    *(f16x8*)(xh + (long long)i * 8) = o;
}

// W1bt[g][n][k], n in [0,2176): n<512 -> Ws[g][k][n] ; n<2048 -> Whh[g][n-512][k] ;
// n-2048<97 -> Wfc[g][n-2048][k] ; else 0.  Also fills fused bias b1.
__global__ void k_pack_w1(const float* __restrict__ Ws, const float* __restrict__ Whh,
                          const float* __restrict__ Wfc, const float* __restrict__ bs,
                          const float* __restrict__ bhh, const float* __restrict__ bfc,
                          _Float16* __restrict__ w1, float* __restrict__ b1) {
    int idx = blockIdx.x * 256 + threadIdx.x;
    if (idx >= 2 * 2176 * 64) return;
    const int k8 = idx & 63;
    const int n  = (idx >> 6) % 2176;
    const int g  = (idx >> 6) / 2176;
    const int k0 = k8 * 8;
    f16x8 o;
    if (n < 512) {
        const float* p = Ws + (long long)g * 512 * 512 + (long long)k0 * 512 + n;
        #pragma unroll
        for (int i = 0; i < 8; ++i) o[i] = (_Float16)p[(long long)i * 512];
    } else if (n < 2048) {
        const float* p = Whh + (long long)g * 1536 * 512 + (long long)(n - 512) * 512 + k0;
        #pragma unroll
        for (int i = 0; i < 8; ++i) o[i] = (_Float16)p[i];
    } else if (n < 2048 + CL_) {
        const float* p = Wfc + (long long)g * CL_ * 512 + (long long)(n - 2048) * 512 + k0;
        #pragma unroll
        for (int i = 0; i < 8; ++i) o[i] = (_Float16)p[i];
    } else {
        #pragma unroll
        for (int i = 0; i < 8; ++i) o[i] = (_Float16)0.0f;
    }
    *(f16x8*)(w1 + ((long long)g * 2176 + n) * 512 + k0) = o;
    if (k8 == 0) {
        float bv = (n < 512) ? bs[g * 512 + n]
                 : (n < 2048) ? bhh[g * 1536 + (n - 512)]
                 : (n < 2048 + CL_) ? bfc[g * CL_ + (n - 2048)] : 0.0f;
        b1[g * 2176 + n] = bv;
    }
}

// W2bt[g][n][k] = Wih[g][n][512+k]  (ctx half of Wih)
__global__ void k_pack_w2(const float* __restrict__ Wih, _Float16* __restrict__ w2) {
    int idx = blockIdx.x * 256 + threadIdx.x;
    if (idx >= 2 * 1536 * 64) return;
    const int k8 = idx & 63;
    const int n  = (idx >> 6) % 1536;
    const int g  = (idx >> 6) / 1536;
    const int k0 = k8 * 8;
    const float* p = Wih + (long long)g * 1536 * 1024 + (long long)n * 1024 + 512 + k0;
    f16x8 o;
    #pragma unroll
    for (int i = 0; i < 8; ++i) o[i] = (_Float16)p[i];
    *(f16x8*)(w2 + ((long long)g * 1536 + n) * 512 + k0) = o;
}

// WxBt[g][n][k] = Wx[g][k][n]
__global__ void k_pack_wx(const float* __restrict__ Wx, _Float16* __restrict__ wx) {
    int idx = blockIdx.x * 256 + threadIdx.x;
    if (idx >= 2 * 512 * 64) return;
    const int k8 = idx & 63;
    const int n  = (idx >> 6) & 511;
    const int g  = (idx >> 6) >> 9;
    const int k0 = k8 * 8;
    const float* p = Wx + (long long)g * 512 * 512 + (long long)k0 * 512 + n;
    f16x8 o;
    #pragma unroll
    for (int i = 0; i < 8; ++i) o[i] = (_Float16)p[(long long)i * 512];
    *(f16x8*)(wx + ((long long)g * 512 + n) * 512 + k0) = o;
}

// embW[g][y][j] = bih[g][j] + sum_a emb[g][y][a] * Wih[g][j][a]   (98 rows only)
__global__ __launch_bounds__(256) void k_emb(const float* __restrict__ emb,
                                             const float* __restrict__ Wih,
                                             const float* __restrict__ bih,
                                             float* __restrict__ eW) {
    const int y = blockIdx.x;   // 0..97
    const int g = blockIdx.y;   // 0..1
    __shared__ float er[512];
    const int tid = threadIdx.x;
    for (int i = tid; i < 512; i += 256) er[i] = emb[(long long)(g * 98 + y) * 512 + i];
    __syncthreads();
    for (int j = tid; j < 1536; j += 256) {
        const float* wr = Wih + (long long)g * 1536 * 1024 + (long long)j * 1024;
        float acc = bih[g * 1536 + j];
        #pragma unroll 8
        for (int a = 0; a < 512; ++a) acc += er[a] * wr[a];
        eW[(long long)(g * 98 + y) * 1536 + j] = acc;
    }
}

// ---------------- GEMM: C[M][N] = A[M][512] * B^T[N][512] (+bias) ----------------
// 128x128 tile, BK=64, 4 waves (2x2), 16x16x32 f16 MFMA, f32 accum.
// Columns >= n_split are routed to lout (logits straight into d_out).
__global__ __launch_bounds__(256) void gemm_bt(
    const _Float16* __restrict__ A, long long aG,
    const _Float16* __restrict__ B, long long bG,
    float* __restrict__ Cf, _Float16* __restrict__ Ch,
    long long cG, int ldc,
    const float* __restrict__ bias, int biasG,
    int nblk_off, int n_split,
    float* __restrict__ lout, int lcols, int lldc)
{
    __shared__ _Float16 As[128][72];   // +8 pad: 144B row stride -> 2-way bank alias (free)
    __shared__ _Float16 Bs[128][72];
    const int g  = blockIdx.z;
    const int m0 = blockIdx.y * 128;
    const int n0 = (blockIdx.x + nblk_off) * 128;
    const _Float16* Ag = A + (long long)g * aG + (long long)m0 * 512;
    const _Float16* Bg = B + (long long)g * bG + (long long)n0 * 512;
    const int tid  = threadIdx.x;
    const int lane = tid & 63, w = tid >> 6;
    const int wr = w >> 1, wc = w & 1;
    const int lr = lane & 15, kg = lane >> 4;
    const int arow = tid >> 3;          // 0..31
    const int acol = (tid & 7) * 8;     // 0..56

    f32x4 acc[4][4];
    #pragma unroll
    for (int m = 0; m < 4; ++m)
        #pragma unroll
        for (int n = 0; n < 4; ++n) acc[m][n] = (f32x4)0.0f;

    for (int kt = 0; kt < 8; ++kt) {
        const int k0 = kt * 64;
        f16x8 ra[4], rb[4];
        #pragma unroll
        for (int i = 0; i < 4; ++i) {
            ra[i] = *(const f16x8*)(Ag + (long long)(arow + i * 32) * 512 + k0 + acol);
            rb[i] = *(const f16x8*)(Bg + (long long)(arow + i * 32) * 512 + k0 + acol);
        }
        __syncthreads();   // all waves done reading previous tile
        #pragma unroll
        for (int i = 0; i < 4; ++i) {
            *(f16x8*)&As[arow + i * 32][acol] = ra[i];
            *(f16x8*)&Bs[arow + i * 32][acol] = rb[i];
        }
        __syncthreads();   // tile visible
        #pragma unroll
        for (int kk = 0; kk < 2; ++kk) {
            f16x8 af[4], bf[4];
            #pragma unroll
            for (int m = 0; m < 4; ++m) af[m] = *(const f16x8*)&As[wr * 64 + m * 16 + lr][kk * 32 + kg * 8];
            #pragma unroll
            for (int n = 0; n < 4; ++n) bf[n] = *(const f16x8*)&Bs[wc * 64 + n * 16 + lr][kk * 32 + kg * 8];
            #pragma unroll
            for (int m = 0; m < 4; ++m)
                #pragma unroll
                for (int n = 0; n < 4; ++n)
                    acc[m][n] = __builtin_amdgcn_mfma_f32_16x16x32_f16(af[m], bf[n], acc[m][n], 0, 0, 0);
        }
    }

    // epilogue: D frag mapping col = lane&15, row = (lane>>4)*4 + i  (m89-verified)
    #pragma unroll
    for (int n = 0; n < 4; ++n) {
        const int col = n0 + wc * 64 + n * 16 + lr;
        const float bb = bias ? bias[g * biasG + col] : 0.0f;
        if (col < n_split) {
            #pragma unroll
            for (int m = 0; m < 4; ++m) {
                const int row = m0 + wr * 64 + m * 16 + kg * 4;
                #pragma unroll
                for (int i = 0; i < 4; ++i) {
                    const long long off = (long long)g * cG + (long long)(row + i) * ldc + col;
                    const float v = acc[m][n][i] + bb;
                    if (Ch) Ch[off] = (_Float16)v; else Cf[off] = v;
                }
            }
        } else if (lout != nullptr) {
            const int c = col - n_split;
            if (c < lcols) {
                #pragma unroll
                for (int m = 0; m < 4; ++m) {
                    const int row = m0 + wr * 64 + m * 16 + kg * 4;
                    #pragma unroll
                    for (int i = 0; i < 4; ++i)
                        lout[(long long)(g * B_ + row + i) * lldc + c] = acc[m][n][i] + bb;
                }
            }
        }
    }
}

// ---------------- fused attention: e = tanh(sProj+xProj)·wv, softmax, ctx ----------------
__global__ __launch_bounds__(256) void k_att(
    const float* __restrict__ Y,        // [2][B][2048]; sProj = cols 0..511
    const _Float16* __restrict__ xpj,   // [2][B][25][512]
    const _Float16* __restrict__ xh,    // [B][25][512]
    const float* __restrict__ wv,       // [2][512]
    _Float16* __restrict__ ctxh)        // [2][B][512]
{
    const int b = blockIdx.x, g = blockIdx.z;
    const int tid = threadIdx.x, lane = tid & 63, w = tid >> 6;
    __shared__ float eL[25];
    const float* sp  = Y + (long long)(g * B_ + b) * 2048;
    const float* wvg = wv + g * 512;
    const int a0 = lane * 8;
    const f32x4 sp0 = *(const f32x4*)(sp + a0);
    const f32x4 sp1 = *(const f32x4*)(sp + a0 + 4);
    const f32x4 wv0 = *(const f32x4*)(wvg + a0);
    const f32x4 wv1 = *(const f32x4*)(wvg + a0 + 4);
    const _Float16* xpb = xpj + (long long)(g * B_ + b) * 25 * 512;
    for (int l = w; l < 25; l += 4) {           // uniform trip count within a wave
        const f16x8 xv = *(const f16x8*)(xpb + l * 512 + a0);
        float part = 0.0f;
        #pragma unroll
        for (int i = 0; i < 4; ++i) {
            part += fast_tanh(sp0[i] + (float)xv[i])     * wv0[i];
            part += fast_tanh(sp1[i] + (float)xv[4 + i]) * wv1[i];
        }
        #pragma unroll
        for (int off = 32; off > 0; off >>= 1) part += __shfl_xor(part, off);
        if (lane == 0) eL[l] = part;            // wvb cancels in softmax -> omitted
    }
    __syncthreads();
    float m = -1e30f;
    #pragma unroll
    for (int l = 0; l < 25; ++l) m = fmaxf(m, eL[l]);
    float al[25], ssum = 0.0f;
    #pragma unroll
    for (int l = 0; l < 25; ++l) { al[l] = __expf(eL[l] - m); ssum += al[l]; }
    const float inv = 1.0f / ssum;
    const _Float16* xb = xh + (long long)b * 25 * 512;
    const int d0 = tid * 2;
    float c0 = 0.0f, c1 = 0.0f;
    #pragma unroll
    for (int l = 0; l < 25; ++l) {
        const f16x2 xv = *(const f16x2*)(xb + l * 512 + d0);
        c0 += al[l] * (float)xv[0];
        c1 += al[l] * (float)xv[1];
    }
    f16x2 o; o[0] = (_Float16)(c0 * inv); o[1] = (_Float16)(c1 * inv);
    *(f16x2*)(ctxh + (long long)(g * B_ + b) * 512 + d0) = o;
}

// ---------------- GRU gate + state update ----------------
__global__ void k_gate(const float* __restrict__ Y,   // gh = cols 512..2047
                       const float* __restrict__ Y2,  // ctxProj [2][B][1536]
                       const float* __restrict__ eW,  // embW [2][98][1536] (incl bih)
                       const int* __restrict__ tgt,   // [2][B][25]
                       float* __restrict__ s32, _Float16* __restrict__ sh, int t)
{
    const int idx = blockIdx.x * 256 + threadIdx.x;
    if (idx >= 2 * B_ * 512) return;
    const int j = idx & 511;
    const int b = (idx >> 9) & (B_ - 1);
    const int g = idx >> 20;
    const int y = (t == 0) ? CL_ : tgt[(g * B_ + b) * T_ + t - 1];
    const float* ew = eW + (long long)(g * 98 + y) * 1536;
    const float* y2 = Y2 + (long long)(g * B_ + b) * 1536;
    const float* yy = Y  + (long long)(g * B_ + b) * 2048;
    const float r  = fast_sigm(ew[j]        + y2[j]        + yy[512 + j]);
    const float z  = fast_sigm(ew[512 + j]  + y2[512 + j]  + yy[1024 + j]);
    const float nn = fast_tanh(ew[1024 + j] + y2[1024 + j] + r * yy[1536 + j]);
    const long long si = (long long)(g * B_ + b) * 512 + j;
    const float sn = (1.0f - z) * nn + z * s32[si];
    s32[si] = sn;
    sh[si]  = (_Float16)sn;
}

// ---------------- launcher ----------------
extern "C" void kernel_launch(void* const* d_in, const int* in_sizes, int n_in,
                              void* d_out, int out_size, void* d_ws, size_t ws_size,
                              hipStream_t stream)
{
    (void)in_sizes; (void)n_in; (void)out_size;
    const float* x   = (const float*)d_in[0];
    const int*   tgt = (const int*)d_in[1];
    const float* Wx  = (const float*)d_in[2];
    const float* bx  = (const float*)d_in[3];
    const float* Wsm = (const float*)d_in[4];
    const float* bs  = (const float*)d_in[5];
    const float* wv  = (const float*)d_in[6];
    // d_in[7] = wvb: cancels in softmax, unused
    const float* emb = (const float*)d_in[8];
    const float* Wih = (const float*)d_in[9];
    const float* bih = (const float*)d_in[10];
    const float* Whh = (const float*)d_in[11];
    const float* bhh = (const float*)d_in[12];
    const float* Wfc = (const float*)d_in[13];
    const float* bfc = (const float*)d_in[14];
    float* out = (float*)d_out;

    char* base = (char*)d_ws;
    size_t off = 0;
    auto alloc = [&](size_t bytes) -> void* {
        void* r = base + off;
        off = (off + bytes + 255) & ~(size_t)255;
        return r;
    };
    _Float16* xh  = (_Float16*)alloc((size_t)B_ * T_ * 512 * 2);          // x fp16
    _Float16* xpj = (_Float16*)alloc((size_t)2 * B_ * T_ * 512 * 2);      // xProj fp16
    _Float16* w1  = (_Float16*)alloc((size_t)2 * 2176 * 512 * 2);         // [Ws|Whh.T|Wfc.T]^T
    _Float16* w2  = (_Float16*)alloc((size_t)2 * 1536 * 512 * 2);         // Wih ctx half
    _Float16* wx  = (_Float16*)alloc((size_t)2 * 512 * 512 * 2);          // Wx^T
    float*    b1  = (float*)alloc((size_t)2 * 2176 * 4);
    float*    eW  = (float*)alloc((size_t)2 * 98 * 1536 * 4);
    float*    s32 = (float*)alloc((size_t)2 * B_ * 512 * 4);
    _Float16* sh  = (_Float16*)alloc((size_t)2 * B_ * 512 * 2);
    _Float16* ctx = (_Float16*)alloc((size_t)2 * B_ * 512 * 2);
    float*    Y   = (float*)alloc((size_t)2 * B_ * 2048 * 4);             // sProj|gh(|logits)
    float*    Y2  = (float*)alloc((size_t)2 * B_ * 1536 * 4);             // ctxProj
    if (off > ws_size) return;  // ws too small -> deterministic fail (diagnosable)

    hipMemsetAsync(s32, 0, (size_t)2 * B_ * 512 * 4, stream);
    hipMemsetAsync(sh,  0, (size_t)2 * B_ * 512 * 2, stream);

    k_convx  <<<12800, 256, 0, stream>>>(x, xh, (B_ * T_ * 512) / 8);
    k_pack_w1<<<1088, 256, 0, stream>>>(Wsm, Whh, Wfc, bs, bhh, bfc, w1, b1);
    k_pack_w2<<<768, 256, 0, stream>>>(Wih, w2);
    k_pack_wx<<<256, 256, 0, stream>>>(Wx, wx);
    k_emb    <<<dim3(98, 2), 256, 0, stream>>>(emb, Wih, bih, eW);

    // xProj[g] = xh @ WxBt[g] + bx[g]  (fp16 out), M=51200, N=512
    gemm_bt<<<dim3(4, 400, 2), 256, 0, stream>>>(
        xh, 0ll, wx, 512ll * 512, nullptr, xpj, (long long)B_ * T_ * 512, 512,
        bx, 512, 0, 1 << 30, nullptr, 0, 0);

    for (int t = 0; t < T_; ++t) {
        // Y = s @ [Ws | Whh.T | Wfc.T] + [bs|bhh|bfc]; logits cols -> out[t-1]
        gemm_bt<<<dim3(t > 0 ? 17 : 16, 16, 2), 256, 0, stream>>>(
            sh, (long long)B_ * 512, w1, 2176ll * 512, Y, nullptr,
            (long long)B_ * 2048, 2048, b1, 2176, 0, 2048,
            t > 0 ? out + (long long)(t - 1) * CL_ : nullptr, CL_, T_ * CL_);
        k_att<<<dim3(B_, 1, 2), 256, 0, stream>>>(Y, xpj, xh, wv, ctx);
        // ctxProj = ctx @ WihCtx.T  (bih folded into embW)
        gemm_bt<<<dim3(12, 16, 2), 256, 0, stream>>>(
            ctx, (long long)B_ * 512, w2, 1536ll * 512, Y2, nullptr,
            (long long)B_ * 1536, 1536, nullptr, 0, 0, 1 << 30, nullptr, 0, 0);
        k_gate<<<8192, 256, 0, stream>>>(Y, Y2, eW, tgt, s32, sh, t);
    }
    // final logits (step T-1) from s_T: only the logits block column
    gemm_bt<<<dim3(1, 16, 2), 256, 0, stream>>>(
        sh, (long long)B_ * 512, w1, 2176ll * 512, Y, nullptr,
        (long long)B_ * 2048, 2048, b1, 2176, 16, 2048,
        out + 24ll * CL_, CL_, T_ * CL_);
}

// Round 2
// 2833.822 us; speedup vs baseline: 1.0089x; 1.0089x over previous
//
#include <hip/hip_runtime.h>
#include <hip/hip_fp16.h>

#define B_ 2048
#define T_ 25
#define CL_ 97

typedef float f32x4 __attribute__((ext_vector_type(4)));
typedef float f32x2 __attribute__((ext_vector_type(2)));
typedef _Float16 f16x8 __attribute__((ext_vector_type(8)));
typedef _Float16 f16x2 __attribute__((ext_vector_type(2)));

#define DI static __device__ __forceinline__

DI float fast_tanh(float x) { return 1.0f - 2.0f / (__expf(2.0f * x) + 1.0f); }
DI float fast_sigm(float x) { return 1.0f / (1.0f + __expf(-x)); }

// async global -> LDS, 16B per lane (global_load_lds_dwordx4). lds base must be
// wave-uniform; each lane writes base + lane*16 (G21 / m97 pattern).
DI void gl16(const void* g, void* l) {
    __builtin_amdgcn_global_load_lds((const __attribute__((address_space(1))) void*)g,
                                     (__attribute__((address_space(3))) void*)l, 16, 0, 0);
}

// ---------------- pack / convert kernels (run once per call) ----------------

__global__ void k_convx(const float* __restrict__ x, _Float16* __restrict__ xh, int n8) {
    int i = blockIdx.x * 256 + threadIdx.x;
    if (i >= n8) return;
    const f32x4 v0 = *(const f32x4*)(x + (long long)i * 8);
    const f32x4 v1 = *(const f32x4*)(x + (long long)i * 8 + 4);
    f16x8 o;
    o[0] = (_Float16)v0[0]; o[1] = (_Float16)v0[1]; o[2] = (_Float16)v0[2]; o[3] = (_Float16)v0[3];
    o[4] = (_Float16)v1[0]; o[5] = (_Float16)v1[1]; o[6] = (_Float16)v1[2]; o[7] = (_Float16)v1[3];
    *(f16x8*)(xh + (long long)i * 8) = o;
}

// W1bt[g][n][k], n in [0,2176): n<512 -> Ws[g][k][n] ; n<2048 -> Whh[g][n-512][k] ;
// n-2048<97 -> Wfc[g][n-2048][k] ; else 0.  Also fills fused bias b1.
__global__ void k_pack_w1(const float* __restrict__ Ws, const float* __restrict__ Whh,
                          const float* __restrict__ Wfc, const float* __restrict__ bs,
                          const float* __restrict__ bhh, const float* __restrict__ bfc,
                          _Float16* __restrict__ w1, float* __restrict__ b1) {
    int idx = blockIdx.x * 256 + threadIdx.x;
    if (idx >= 2 * 2176 * 64) return;
    const int k8 = idx & 63;
    const int n  = (idx >> 6) % 2176;
    const int g  = (idx >> 6) / 2176;
    const int k0 = k8 * 8;
    f16x8 o;
    if (n < 512) {
        const float* p = Ws + (long long)g * 512 * 512 + (long long)k0 * 512 + n;
        #pragma unroll
        for (int i = 0; i < 8; ++i) o[i] = (_Float16)p[(long long)i * 512];
    } else if (n < 2048) {
        const float* p = Whh + (long long)g * 1536 * 512 + (long long)(n - 512) * 512 + k0;
        #pragma unroll
        for (int i = 0; i < 8; ++i) o[i] = (_Float16)p[i];
    } else if (n < 2048 + CL_) {
        const float* p = Wfc + (long long)g * CL_ * 512 + (long long)(n - 2048) * 512 + k0;
        #pragma unroll
        for (int i = 0; i < 8; ++i) o[i] = (_Float16)p[i];
    } else {
        #pragma unroll
        for (int i = 0; i < 8; ++i) o[i] = (_Float16)0.0f;
    }
    *(f16x8*)(w1 + ((long long)g * 2176 + n) * 512 + k0) = o;
    if (k8 == 0) {
        float bv = (n < 512) ? bs[g * 512 + n]
                 : (n < 2048) ? bhh[g * 1536 + (n - 512)]
                 : (n < 2048 + CL_) ? bfc[g * CL_ + (n - 2048)] : 0.0f;
        b1[g * 2176 + n] = bv;
    }
}

// w2[g][n][k] = Wih[g][n][512+k] (ctx half); w2e[g][n][k] = Wih[g][n][k] (emb half)
__global__ void k_pack_w2(const float* __restrict__ Wih, _Float16* __restrict__ w2,
                          _Float16* __restrict__ w2e) {
    int idx = blockIdx.x * 256 + threadIdx.x;
    if (idx >= 2 * 1536 * 64) return;
    const int k8 = idx & 63;
    const int n  = (idx >> 6) % 1536;
    const int g  = (idx >> 6) / 1536;
    const int k0 = k8 * 8;
    const float* p = Wih + (long long)g * 1536 * 1024 + (long long)n * 1024;
    f16x8 o, oe;
    #pragma unroll
    for (int i = 0; i < 8; ++i) { o[i] = (_Float16)p[512 + k0 + i]; oe[i] = (_Float16)p[k0 + i]; }
    *(f16x8*)(w2  + ((long long)g * 1536 + n) * 512 + k0) = o;
    *(f16x8*)(w2e + ((long long)g * 1536 + n) * 512 + k0) = oe;
}

// WxBt[g][n][k] = Wx[g][k][n]
__global__ void k_pack_wx(const float* __restrict__ Wx, _Float16* __restrict__ wx) {
    int idx = blockIdx.x * 256 + threadIdx.x;
    if (idx >= 2 * 512 * 64) return;
    const int k8 = idx & 63;
    const int n  = (idx >> 6) & 511;
    const int g  = (idx >> 6) >> 9;
    const int k0 = k8 * 8;
    const float* p = Wx + (long long)g * 512 * 512 + (long long)k0 * 512 + n;
    f16x8 o;
    #pragma unroll
    for (int i = 0; i < 8; ++i) o[i] = (_Float16)p[(long long)i * 512];
    *(f16x8*)(wx + ((long long)g * 512 + n) * 512 + k0) = o;
}

// embh[g][y][k]: emb fp16 padded to 128 rows (rows 98..127 = 0)
__global__ void k_pack_emb(const float* __restrict__ emb, _Float16* __restrict__ embh) {
    int i = blockIdx.x * 256 + threadIdx.x;
    if (i >= 2 * 128 * 64) return;
    const int k8 = i & 63;
    const int y  = (i >> 6) & 127;
    const int g  = i >> 13;
    f16x8 o;
    if (y < 98) {
        const float* p = emb + (long long)(g * 98 + y) * 512 + k8 * 8;
        #pragma unroll
        for (int j = 0; j < 8; ++j) o[j] = (_Float16)p[j];
    } else {
        #pragma unroll
        for (int j = 0; j < 8; ++j) o[j] = (_Float16)0.0f;
    }
    *(f16x8*)(embh + (long long)(g * 128 + y) * 512 + k8 * 8) = o;
}

// ---------------- GEMM: C[M][N] = A[M][512] * B^T[N][512] (+bias) ----------------
// 128x128 tile, BK=64, 4 waves (2x2), 16x16x32 f16 MFMA, f32 accum.
// Staging: global_load_lds width=16 into linear LDS (m97 structure).
// Columns >= n_split are routed to lout (logits straight into d_out, f32).
__global__ __launch_bounds__(256) void gemm_bt(
    const _Float16* __restrict__ A, long long aG,
    const _Float16* __restrict__ B, long long bG,
    float* __restrict__ Cf, _Float16* __restrict__ Ch,
    long long cG, int ldc,
    const float* __restrict__ bias, int biasG,
    int nblk_off, int n_split,
    float* __restrict__ lout, int lcols, int lldc)
{
    __shared__ _Float16 As[128 * 64];   // linear: gload_lds needs contiguous dest (G21)
    __shared__ _Float16 Bs[128 * 64];
    const int g  = blockIdx.z;
    const int m0 = blockIdx.y * 128;
    const int n0 = (blockIdx.x + nblk_off) * 128;
    const _Float16* Ag = A + (long long)g * aG + (long long)m0 * 512;
    const _Float16* Bg = B + (long long)g * bG + (long long)n0 * 512;
    const int tid  = threadIdx.x;
    const int lane = tid & 63, w = tid >> 6;
    const int wr = w >> 1, wc = w & 1;
    const int lr = lane & 15, kg = lane >> 4;
    const int srow = (lane >> 3);        // 0..7 within an 8-row chunk
    const int scol = (lane & 7) * 8;     // element col 0..56

    f32x4 acc[4][4];
    #pragma unroll
    for (int m = 0; m < 4; ++m)
        #pragma unroll
        for (int n = 0; n < 4; ++n) acc[m][n] = (f32x4)0.0f;

    for (int kt = 0; kt < 8; ++kt) {
        const int k0 = kt * 64;
        __syncthreads();   // all waves done reading previous tile
        #pragma unroll
        for (int cc = 0; cc < 4; ++cc) {
            const int r = w * 32 + cc * 8;
            gl16(Ag + (long long)(r + srow) * 512 + k0 + scol, &As[r * 64]);
            gl16(Bg + (long long)(r + srow) * 512 + k0 + scol, &Bs[r * 64]);
        }
        __syncthreads();   // compiler drains vmcnt(0) before barrier -> tile visible
        #pragma unroll
        for (int kk = 0; kk < 2; ++kk) {
            f16x8 af[4], bf[4];
            #pragma unroll
            for (int m = 0; m < 4; ++m) af[m] = *(const f16x8*)&As[(wr * 64 + m * 16 + lr) * 64 + kk * 32 + kg * 8];
            #pragma unroll
            for (int n = 0; n < 4; ++n) bf[n] = *(const f16x8*)&Bs[(wc * 64 + n * 16 + lr) * 64 + kk * 32 + kg * 8];
            #pragma unroll
            for (int m = 0; m < 4; ++m)
                #pragma unroll
                for (int n = 0; n < 4; ++n)
                    acc[m][n] = __builtin_amdgcn_mfma_f32_16x16x32_f16(af[m], bf[n], acc[m][n], 0, 0, 0);
        }
    }

    // epilogue: D frag mapping col = lane&15, row = (lane>>4)*4 + i  (m89-verified)
    #pragma unroll
    for (int n = 0; n < 4; ++n) {
        const int col = n0 + wc * 64 + n * 16 + lr;
        const float bb = bias ? bias[g * biasG + col] : 0.0f;
        if (col < n_split) {
            #pragma unroll
            for (int m = 0; m < 4; ++m) {
                const int row = m0 + wr * 64 + m * 16 + kg * 4;
                #pragma unroll
                for (int i = 0; i < 4; ++i) {
                    const long long off = (long long)g * cG + (long long)(row + i) * ldc + col;
                    const float v = acc[m][n][i] + bb;
                    if (Ch) Ch[off] = (_Float16)v; else Cf[off] = v;
                }
            }
        } else if (lout != nullptr) {
            const int c = col - n_split;
            if (c < lcols) {
                #pragma unroll
                for (int m = 0; m < 4; ++m) {
                    const int row = m0 + wr * 64 + m * 16 + kg * 4;
                    #pragma unroll
                    for (int i = 0; i < 4; ++i)
                        lout[(long long)(g * B_ + row + i) * lldc + c] = acc[m][n][i] + bb;
                }
            }
        }
    }
}

// ---------------- fused attention: e = tanh(sProj+xProj)·wv, softmax, ctx ----------------
__global__ __launch_bounds__(256) void k_att(
    const _Float16* __restrict__ Yh,    // [2][B][2048] fp16; sProj = cols 0..511
    const _Float16* __restrict__ xpj,   // [2][B][25][512]
    const _Float16* __restrict__ xh,    // [B][25][512]
    const float* __restrict__ wv,       // [2][512]
    _Float16* __restrict__ ctxh)        // [2][B][512]
{
    const int b = blockIdx.x, g = blockIdx.z;
    const int tid = threadIdx.x, lane = tid & 63, w = tid >> 6;
    __shared__ float eL[25];
    const _Float16* sp = Yh + (long long)(g * B_ + b) * 2048;
    const float* wvg = wv + g * 512;
    const int a0 = lane * 8;
    const f16x8 spv = *(const f16x8*)(sp + a0);
    const f32x4 wv0 = *(const f32x4*)(wvg + a0);
    const f32x4 wv1 = *(const f32x4*)(wvg + a0 + 4);
    const _Float16* xpb = xpj + (long long)(g * B_ + b) * 25 * 512;
    for (int l = w; l < 25; l += 4) {           // uniform trip count within a wave
        const f16x8 xv = *(const f16x8*)(xpb + l * 512 + a0);
        float part = 0.0f;
        #pragma unroll
        for (int i = 0; i < 4; ++i) {
            part += fast_tanh((float)spv[i]     + (float)xv[i])     * wv0[i];
            part += fast_tanh((float)spv[4 + i] + (float)xv[4 + i]) * wv1[i];
        }
        #pragma unroll
        for (int off = 32; off > 0; off >>= 1) part += __shfl_xor(part, off);
        if (lane == 0) eL[l] = part;            // wvb cancels in softmax -> omitted
    }
    __syncthreads();
    float m = -1e30f;
    #pragma unroll
    for (int l = 0; l < 25; ++l) m = fmaxf(m, eL[l]);
    float al[25], ssum = 0.0f;
    #pragma unroll
    for (int l = 0; l < 25; ++l) { al[l] = __expf(eL[l] - m); ssum += al[l]; }
    const float inv = 1.0f / ssum;
    const _Float16* xb = xh + (long long)b * 25 * 512;
    const int d0 = tid * 2;
    float c0 = 0.0f, c1 = 0.0f;
    #pragma unroll
    for (int l = 0; l < 25; ++l) {
        const f16x2 xv = *(const f16x2*)(xb + l * 512 + d0);
        c0 += al[l] * (float)xv[0];
        c1 += al[l] * (float)xv[1];
    }
    f16x2 o; o[0] = (_Float16)(c0 * inv); o[1] = (_Float16)(c1 * inv);
    *(f16x2*)(ctxh + (long long)(g * B_ + b) * 512 + d0) = o;
}

// ---------------- GRU gate + state update (2 cols per thread) ----------------
__global__ void k_gate(const _Float16* __restrict__ Yh,  // gh = cols 512..2047
                       const _Float16* __restrict__ Y2h, // ctxProj [2][B][1536]
                       const float* __restrict__ eW,     // embW [2][128][1536] (incl bih)
                       const int* __restrict__ tgt,      // [2][B][25]
                       float* __restrict__ s32, _Float16* __restrict__ sh, int t)
{
    const int idx = blockIdx.x * 256 + threadIdx.x;
    if (idx >= 2 * B_ * 256) return;
    const int jp = (idx & 255) * 2;
    const int b  = (idx >> 8) & (B_ - 1);
    const int g  = idx >> 19;
    const int y  = (t == 0) ? CL_ : tgt[(g * B_ + b) * T_ + t - 1];
    const float*    ew = eW  + (long long)(g * 128 + y) * 1536;
    const _Float16* y2 = Y2h + (long long)(g * B_ + b) * 1536;
    const _Float16* yy = Yh  + (long long)(g * B_ + b) * 2048;
    const f32x2 ewr = *(const f32x2*)(ew + jp);
    const f32x2 ewz = *(const f32x2*)(ew + 512 + jp);
    const f32x2 ewn = *(const f32x2*)(ew + 1024 + jp);
    const f16x2 y2r = *(const f16x2*)(y2 + jp);
    const f16x2 y2z = *(const f16x2*)(y2 + 512 + jp);
    const f16x2 y2n = *(const f16x2*)(y2 + 1024 + jp);
    const f16x2 ghr = *(const f16x2*)(yy + 512 + jp);
    const f16x2 ghz = *(const f16x2*)(yy + 1024 + jp);
    const f16x2 ghn = *(const f16x2*)(yy + 1536 + jp);
    const long long si = (long long)(g * B_ + b) * 512 + jp;
    const f32x2 so = *(const f32x2*)(s32 + si);
    f32x2 sn;
    f16x2 snh;
    #pragma unroll
    for (int i = 0; i < 2; ++i) {
        const float r  = fast_sigm(ewr[i] + (float)y2r[i] + (float)ghr[i]);
        const float z  = fast_sigm(ewz[i] + (float)y2z[i] + (float)ghz[i]);
        const float nn = fast_tanh(ewn[i] + (float)y2n[i] + r * (float)ghn[i]);
        sn[i]  = (1.0f - z) * nn + z * so[i];
        snh[i] = (_Float16)sn[i];
    }
    *(f32x2*)(s32 + si) = sn;
    *(f16x2*)(sh + si) = snh;
}

// ---------------- launcher ----------------
extern "C" void kernel_launch(void* const* d_in, const int* in_sizes, int n_in,
                              void* d_out, int out_size, void* d_ws, size_t ws_size,
                              hipStream_t stream)
{
    (void)in_sizes; (void)n_in; (void)out_size;
    const float* x   = (const float*)d_in[0];
    const int*   tgt = (const int*)d_in[1];
    const float* Wx  = (const float*)d_in[2];
    const float* bx  = (const float*)d_in[3];
    const float* Wsm = (const float*)d_in[4];
    const float* bs  = (const float*)d_in[5];
    const float* wv  = (const float*)d_in[6];
    // d_in[7] = wvb: cancels in softmax, unused
    const float* emb = (const float*)d_in[8];
    const float* Wih = (const float*)d_in[9];
    const float* bih = (const float*)d_in[10];
    const float* Whh = (const float*)d_in[11];
    const float* bhh = (const float*)d_in[12];
    const float* Wfc = (const float*)d_in[13];
    const float* bfc = (const float*)d_in[14];
    float* out = (float*)d_out;

    char* base = (char*)d_ws;
    size_t off = 0;
    auto alloc = [&](size_t bytes) -> void* {
        void* r = base + off;
        off = (off + bytes + 255) & ~(size_t)255;
        return r;
    };
    _Float16* xh   = (_Float16*)alloc((size_t)B_ * T_ * 512 * 2);          // x fp16
    _Float16* xpj  = (_Float16*)alloc((size_t)2 * B_ * T_ * 512 * 2);      // xProj fp16
    _Float16* w1   = (_Float16*)alloc((size_t)2 * 2176 * 512 * 2);         // [Ws|Whh.T|Wfc.T]^T
    _Float16* w2   = (_Float16*)alloc((size_t)2 * 1536 * 512 * 2);         // Wih ctx half
    _Float16* w2e  = (_Float16*)alloc((size_t)2 * 1536 * 512 * 2);         // Wih emb half
    _Float16* wx   = (_Float16*)alloc((size_t)2 * 512 * 512 * 2);          // Wx^T
    _Float16* embh = (_Float16*)alloc((size_t)2 * 128 * 512 * 2);          // emb fp16, M-padded
    float*    b1   = (float*)alloc((size_t)2 * 2176 * 4);
    float*    eW   = (float*)alloc((size_t)2 * 128 * 1536 * 4);            // embW (128-row stride)
    float*    s32  = (float*)alloc((size_t)2 * B_ * 512 * 4);
    _Float16* sh   = (_Float16*)alloc((size_t)2 * B_ * 512 * 2);
    _Float16* ctx  = (_Float16*)alloc((size_t)2 * B_ * 512 * 2);
    _Float16* Yh   = (_Float16*)alloc((size_t)2 * B_ * 2048 * 2);          // sProj|gh fp16
    _Float16* Y2h  = (_Float16*)alloc((size_t)2 * B_ * 1536 * 2);          // ctxProj fp16
    if (off > ws_size) return;  // ws too small -> deterministic fail (diagnosable)

    hipMemsetAsync(s32, 0, (size_t)2 * B_ * 512 * 4, stream);
    hipMemsetAsync(sh,  0, (size_t)2 * B_ * 512 * 2, stream);

    k_convx   <<<12800, 256, 0, stream>>>(x, xh, (B_ * T_ * 512) / 8);
    k_pack_w1 <<<1088, 256, 0, stream>>>(Wsm, Whh, Wfc, bs, bhh, bfc, w1, b1);
    k_pack_w2 <<<768, 256, 0, stream>>>(Wih, w2, w2e);
    k_pack_wx <<<256, 256, 0, stream>>>(Wx, wx);
    k_pack_emb<<<64, 256, 0, stream>>>(emb, embh);

    // embW = embh @ w2e^T + bih : M=128, N=1536  (replaces 129us k_emb)
    gemm_bt<<<dim3(12, 1, 2), 256, 0, stream>>>(
        embh, 128ll * 512, w2e, 1536ll * 512, eW, nullptr,
        128ll * 1536, 1536, bih, 1536, 0, 1 << 30, nullptr, 0, 0);

    // xProj[g] = xh @ WxBt[g] + bx[g]  (fp16 out), M=51200, N=512
    gemm_bt<<<dim3(4, 400, 2), 256, 0, stream>>>(
        xh, 0ll, wx, 512ll * 512, nullptr, xpj, (long long)B_ * T_ * 512, 512,
        bx, 512, 0, 1 << 30, nullptr, 0, 0);

    for (int t = 0; t < T_; ++t) {
        // Y = s @ [Ws | Whh.T | Wfc.T] + [bs|bhh|bfc]; logits cols -> out[t-1]
        gemm_bt<<<dim3(t > 0 ? 17 : 16, 16, 2), 256, 0, stream>>>(
            sh, (long long)B_ * 512, w1, 2176ll * 512, nullptr, Yh,
            (long long)B_ * 2048, 2048, b1, 2176, 0, 2048,
            t > 0 ? out + (long long)(t - 1) * CL_ : nullptr, CL_, T_ * CL_);
        k_att<<<dim3(B_, 1, 2), 256, 0, stream>>>(Yh, xpj, xh, wv, ctx);
        // ctxProj = ctx @ WihCtx.T  (bih folded into embW)
        gemm_bt<<<dim3(12, 16, 2), 256, 0, stream>>>(
            ctx, (long long)B_ * 512, w2, 1536ll * 512, nullptr, Y2h,
            (long long)B_ * 1536, 1536, nullptr, 0, 0, 1 << 30, nullptr, 0, 0);
        k_gate<<<4096, 256, 0, stream>>>(Yh, Y2h, eW, tgt, s32, sh, t);
    }
    // final logits (step T-1) from s_T: only the logits block column
    gemm_bt<<<dim3(1, 16, 2), 256, 0, stream>>>(
        sh, (long long)B_ * 512, w1, 2176ll * 512, nullptr, Yh,
        (long long)B_ * 2048, 2048, b1, 2176, 16, 2048,
        out + 24ll * CL_, CL_, T_ * CL_);
}